// Round 2
// baseline (288.418 us; speedup 1.0000x reference)
//
#include <hip/hip_runtime.h>

#define T_STEPS 128
#define CIN     16
#define HH      64
#define WW      64
#define COUT    64
#define HWSZ    (HH * WW)          // 4096
#define CHW     (COUT * HWSZ)      // 262144
#define XCHW    (CIN * HWSZ)       // 65536

#define TILE    32

// ---- setup: W[64][16][3][3] -> Wtr[(co>>2)*16+ci][ky][co&3][kx] (36 floats) ----
// Per (g4=co>>2, ci): 36 floats, dr-major: offset = ky*12 + (co&3)*3 + kx.
// Base (g4*16+ci)*36 floats = *144 B (16-aligned); +ky*48 B keeps float4 alignment.
__global__ void transpose_w(const float* __restrict__ W, float* __restrict__ Wtr) {
    int e = blockIdx.x * 256 + threadIdx.x;     // 0..9215
    if (e >= COUT * CIN * 9) return;
    int co = e / (CIN * 9);
    int r  = e - co * (CIN * 9);
    int ci = r / 9;
    int k  = r - ci * 9;
    int ky = k / 3;
    int kx = k - ky * 3;
    Wtr[((co >> 2) * CIN + ci) * 36 + ky * 12 + (co & 3) * 3 + kx] = W[e];
}

// pass-1, no-LDS variant: x read directly through L1 (per-ci tile footprint
// 4.6 KB, ~18x block reuse). No barriers, no staging lockstep, no bank
// conflicts. Weights stay s_load'd (block-uniform address), 12 floats live.
// acc[16][4] -> AGPRs (unified file); total regs ~<=128 -> 4 waves/SIMD.
__global__ __launch_bounds__(512, 4)
void spiking_conv_pass1(const float* __restrict__ x, const float* __restrict__ Wtr,
                        const float* __restrict__ b, float* __restrict__ out) {
    const int tid = threadIdx.x;        // 0..511
    const int t   = blockIdx.y;
    const int h0  = (blockIdx.x >> 1) * TILE;
    const int w0  = (blockIdx.x & 1) * TILE;
    const int coh = blockIdx.z;         // 0/1: 32-co half

    const int cog = __builtin_amdgcn_readfirstlane(tid >> 8);  // 0/1
    const int sp  = tid & 255;
    const int pr0 = sp >> 3;            // 0..31
    const int pc0 = (sp & 7) * 4;       // 0..28

    const float* xt = x + t * XCHW;
    float* outt = out + t * CHW;

    float acc[16][4];
#pragma unroll
    for (int j = 0; j < 16; ++j)
#pragma unroll
        for (int p = 0; p < 4; ++p) acc[j][p] = 0.f;

    const int gw0 = w0 + pc0;                   // aligned float4 col base
    const bool colL = (gw0 > 0);                // left edge scalar valid
    const bool colR = (gw0 + 4 < WW);           // right edge scalar valid
    const int gwl = colL ? gw0 - 1 : 0;         // clamped safe addresses
    const int gwr = colR ? gw0 + 4 : WW - 1;

#pragma unroll 1
    for (int ci = 0; ci < CIN; ++ci) {
        // ---- load 3x6 x patch straight from global (L1-resident tile) ----
        float xv[3][6];
#pragma unroll
        for (int dr = 0; dr < 3; ++dr) {
            const int gh = h0 + pr0 + dr - 1;
            const bool rowOK = (unsigned)gh < (unsigned)HH;
            const int ghc = rowOK ? gh : 0;     // clamped safe row
            const float* rp = xt + ci * HWSZ + ghc * WW;
            float4 m  = *(const float4*)(rp + gw0);
            float  xl = rp[gwl];
            float  xr = rp[gwr];
            xv[dr][0] = (rowOK && colL) ? xl : 0.f;
            xv[dr][1] = rowOK ? m.x : 0.f;
            xv[dr][2] = rowOK ? m.y : 0.f;
            xv[dr][3] = rowOK ? m.z : 0.f;
            xv[dr][4] = rowOK ? m.w : 0.f;
            xv[dr][5] = (rowOK && colR) ? xr : 0.f;
        }
        // ---- FMA: dr-major to match Wtr layout; order (ci,ky,kx) preserved ----
#pragma unroll
        for (int dr = 0; dr < 3; ++dr) {
#pragma unroll
            for (int g = 0; g < 4; ++g) {
                const int g4 = coh * 8 + cog * 4 + g;      // block-uniform
                const float* wr = Wtr + (g4 * CIN + ci) * 36 + dr * 12;
                float4 wA = *(const float4*)(wr);
                float4 wB = *(const float4*)(wr + 4);
                float4 wC = *(const float4*)(wr + 8);
                const float wf[12] = {wA.x, wA.y, wA.z, wA.w,
                                      wB.x, wB.y, wB.z, wB.w,
                                      wC.x, wC.y, wC.z, wC.w};
#pragma unroll
                for (int jj = 0; jj < 4; ++jj)
#pragma unroll
                    for (int kx = 0; kx < 3; ++kx) {
                        const float wv = wf[jj * 3 + kx];
#pragma unroll
                        for (int p = 0; p < 4; ++p)
                            acc[g * 4 + jj][p] += wv * xv[dr][kx + p];
                    }
            }
        }
    }

    // ---- epilogue: +bias, float4 stores ----
#pragma unroll
    for (int g = 0; g < 4; ++g)
#pragma unroll
        for (int jj = 0; jj < 4; ++jj) {
            const int co = coh * 32 + cog * 16 + g * 4 + jj;
            const float bias = b[co];
            float4 o;
            o.x = acc[g * 4 + jj][0] + bias;
            o.y = acc[g * 4 + jj][1] + bias;
            o.z = acc[g * 4 + jj][2] + bias;
            o.w = acc[g * 4 + jj][3] + bias;
            *(float4*)&outt[co * HWSZ + (h0 + pr0) * WW + (w0 + pc0)] = o;
        }
}

// In-place scan, ping-pong A/B batches of 8 t. Refills are issued AFTER each
// process/store group, so every wait is a counted vmcnt (never a full drain):
// waiting for A leaves B + stores outstanding. Steady state: 8-16 loads +
// 8 stores in flight per thread. Stores are nontemporal (spikes never
// re-read; keep L2/L3 for the read stream).
__global__ __launch_bounds__(256)
void spiking_scan_pass2(float* __restrict__ io) {
    const int idx = blockIdx.x * 256 + threadIdx.x;   // 0..262143
    float* p = io + idx;                              // column stride CHW
    float s = 0.f;
    float A[8], B[8];
#pragma unroll
    for (int i = 0; i < 8; ++i) A[i] = p[(size_t)i * CHW];
#pragma unroll
    for (int i = 0; i < 8; ++i) B[i] = p[(size_t)(8 + i) * CHW];
#pragma unroll 1
    for (int tb = 0; tb < 7; ++tb) {
        const size_t base = (size_t)tb * 16 * CHW;
#pragma unroll
        for (int i = 0; i < 8; ++i) {
            s += A[i];
            bool a = (s >= 8.0f);
            float o = a ? 1.f : 0.f;
            s = a ? 0.f : s;
            s = fmaxf(s, -1.f);
            __builtin_nontemporal_store(o, &p[base + (size_t)i * CHW]);
        }
#pragma unroll
        for (int i = 0; i < 8; ++i) A[i] = p[base + (size_t)(16 + i) * CHW];
#pragma unroll
        for (int i = 0; i < 8; ++i) {
            s += B[i];
            bool a = (s >= 8.0f);
            float o = a ? 1.f : 0.f;
            s = a ? 0.f : s;
            s = fmaxf(s, -1.f);
            __builtin_nontemporal_store(o, &p[base + (size_t)(8 + i) * CHW]);
        }
#pragma unroll
        for (int i = 0; i < 8; ++i) B[i] = p[base + (size_t)(24 + i) * CHW];
    }
    {   // tail: t = 112..127, no refill
        const size_t base = (size_t)112 * CHW;
#pragma unroll
        for (int i = 0; i < 8; ++i) {
            s += A[i];
            bool a = (s >= 8.0f);
            float o = a ? 1.f : 0.f;
            s = a ? 0.f : s;
            s = fmaxf(s, -1.f);
            __builtin_nontemporal_store(o, &p[base + (size_t)i * CHW]);
        }
#pragma unroll
        for (int i = 0; i < 8; ++i) {
            s += B[i];
            bool a = (s >= 8.0f);
            float o = a ? 1.f : 0.f;
            s = a ? 0.f : s;
            s = fmaxf(s, -1.f);
            __builtin_nontemporal_store(o, &p[base + (size_t)(8 + i) * CHW]);
        }
    }
}

extern "C" void kernel_launch(void* const* d_in, const int* in_sizes, int n_in,
                              void* d_out, int out_size, void* d_ws, size_t ws_size,
                              hipStream_t stream) {
    const float* x = (const float*)d_in[0];   // [128,16,64,64]
    const float* W = (const float*)d_in[1];   // [64,16,3,3]
    const float* b = (const float*)d_in[2];   // [64]
    float* out = (float*)d_out;               // [128,64,64,64]
    float* Wtr = (float*)d_ws;                // 16*16*36*4 = 36864 B

    transpose_w<<<36, 256, 0, stream>>>(W, Wtr);

    dim3 g1(4, 128, 2);   // 4 tiles x 128 t x 2 co-halves = 1024 blocks
    spiking_conv_pass1<<<g1, 512, 0, stream>>>(x, Wtr, b, out);

    spiking_scan_pass2<<<CHW / 256, 256, 0, stream>>>(out);
}

// Round 4
// 275.668 us; speedup vs baseline: 1.0463x; 1.0463x over previous
//
#include <hip/hip_runtime.h>

#define T_STEPS 128
#define CIN     16
#define HH      64
#define WW      64
#define COUT    64
#define HWSZ    (HH * WW)          // 4096
#define CHW     (COUT * HWSZ)      // 262144
#define XCHW    (CIN * HWSZ)       // 65536

// pass-1: block = one t, 32x32 tile, 32-co half; wave-halves own 16 co each.
#define TILE    32
#define HALO    34
#define LSTR    36                  // padded LDS row stride (floats)
#define PLANE   (HALO * LSTR)       // 1224 floats per ci
#define NST     (CIN * HALO * HALO) // 18496 staged elements
#define WBLK    40                  // padded weight block per (co-group-of-4, ci)

typedef float vfloat4 __attribute__((ext_vector_type(4)));  // native vec for NT store

// ---- setup: W[64][16][3][3] -> Wtr[(co>>2)*16+ci][40], inner (co&3)*9+k ----
__global__ void transpose_w(const float* __restrict__ W, float* __restrict__ Wtr) {
    int e = blockIdx.x * 256 + threadIdx.x;     // 0..9215
    if (e >= COUT * CIN * 9) return;
    int co = e / (CIN * 9);
    int r  = e - co * (CIN * 9);
    int ci = r / 9;
    int k  = r - ci * 9;
    Wtr[((co >> 2) * CIN + ci) * WBLK + (co & 3) * 9 + k] = W[e];
}

// R0 LDS-staged conv (proven 120 us), with the co-half as a kernel arg so the
// two halves launch separately (makes pass2 the longest dispatch -> visible
// in top-5 counters).
__global__ __launch_bounds__(512, 4)
void spiking_conv_pass1(const float* __restrict__ x, const float* __restrict__ Wtr,
                        const float* __restrict__ b, float* __restrict__ out,
                        const int coh) {
    __shared__ float xs[CIN * PLANE];   // 78336 B -> 2 blocks/CU, 16 waves/CU

    const int tid = threadIdx.x;        // 0..511
    const int t   = blockIdx.y;
    const int h0  = (blockIdx.x >> 1) * TILE;
    const int w0  = (blockIdx.x & 1) * TILE;

    // ---- stage all 16 ci (+halo); two unrolled load-batches, loads in flight ----
    const float* xt = x + t * XCHW;
    {
        float vbuf[19]; int ibuf[19];
#pragma unroll
        for (int k = 0; k < 18; ++k) {
            unsigned e = tid + k * 512;
            unsigned ci = e / (HALO * HALO);
            unsigned rem = e - ci * (HALO * HALO);
            unsigned r  = rem / HALO;
            unsigned c  = rem - r * HALO;
            int gh = h0 - 1 + (int)r;
            int gw = w0 - 1 + (int)c;
            bool inb = (unsigned)gh < HH && (unsigned)gw < WW;
            vbuf[k] = inb ? xt[ci * HWSZ + gh * WW + gw] : 0.f;
            ibuf[k] = ci * PLANE + r * LSTR + c;
        }
#pragma unroll
        for (int k = 0; k < 18; ++k) xs[ibuf[k]] = vbuf[k];
#pragma unroll
        for (int k = 0; k < 19; ++k) {
            unsigned e = tid + (18 + k) * 512;
            unsigned ci = e / (HALO * HALO);
            unsigned rem = e - ci * (HALO * HALO);
            unsigned r  = rem / HALO;
            unsigned c  = rem - r * HALO;
            int gh = h0 - 1 + (int)r;
            int gw = w0 - 1 + (int)c;
            bool inb = e < NST && (unsigned)gh < HH && (unsigned)gw < WW;
            vbuf[k] = inb ? xt[ci * HWSZ + gh * WW + gw] : 0.f;
            ibuf[k] = (e < NST) ? (int)(ci * PLANE + r * LSTR + c) : -1;
        }
#pragma unroll
        for (int k = 0; k < 19; ++k)
            if (ibuf[k] >= 0) xs[ibuf[k]] = vbuf[k];
    }
    __syncthreads();

    // ---- compute: wave-half picks 16-co group; thread = 1x4 patch ----
    const int cog = __builtin_amdgcn_readfirstlane(tid >> 8);  // 0/1
    const int sp  = tid & 255;
    const int pr0 = sp >> 3;           // 0..31
    const int pc0 = (sp & 7) * 4;      // 0..28
    float* outt = out + t * CHW;

    float acc[16][4];
#pragma unroll
    for (int j = 0; j < 16; ++j)
#pragma unroll
        for (int p = 0; p < 4; ++p) acc[j][p] = 0.f;

#pragma unroll 1
    for (int ci = 0; ci < CIN; ++ci) {
        // x patch 3x6: ds_read_b128 + ds_read_b64 per row
        float xv[3][6];
#pragma unroll
        for (int dr = 0; dr < 3; ++dr) {
            const float* row = &xs[ci * PLANE + (pr0 + dr) * LSTR + pc0];
            float4 a  = *(const float4*)row;
            float2 c2 = *(const float2*)(row + 4);
            xv[dr][0] = a.x;  xv[dr][1] = a.y;
            xv[dr][2] = a.z;  xv[dr][3] = a.w;
            xv[dr][4] = c2.x; xv[dr][5] = c2.y;
        }
        // 4 co-groups of 4: contiguous 36-float scalar loads (wide s_load)
#pragma unroll
        for (int g = 0; g < 4; ++g) {
            const int g4 = coh * 8 + cog * 4 + g;          // launch/block-uniform
            const float* wb = Wtr + (g4 * CIN + ci) * WBLK;
            float w[36];
#pragma unroll
            for (int i = 0; i < 36; ++i) w[i] = wb[i];
#pragma unroll
            for (int jj = 0; jj < 4; ++jj)
#pragma unroll
                for (int ky = 0; ky < 3; ++ky)
#pragma unroll
                    for (int kx = 0; kx < 3; ++kx) {
                        const float wv = w[jj * 9 + ky * 3 + kx];
#pragma unroll
                        for (int p = 0; p < 4; ++p)
                            acc[g * 4 + jj][p] += wv * xv[ky][kx + p];
                    }
        }
    }

    // ---- epilogue: +bias, float4 stores ----
#pragma unroll
    for (int g = 0; g < 4; ++g)
#pragma unroll
        for (int jj = 0; jj < 4; ++jj) {
            const int co = coh * 32 + cog * 16 + g * 4 + jj;
            const float bias = b[co];
            float4 o;
            o.x = acc[g * 4 + jj][0] + bias;
            o.y = acc[g * 4 + jj][1] + bias;
            o.z = acc[g * 4 + jj][2] + bias;
            o.w = acc[g * 4 + jj][3] + bias;
            *(float4*)&outt[co * HWSZ + (h0 + pr0) * WW + (w0 + pc0)] = o;
        }
}

// Scan, R0 float4-batch structure, src/dst split. Out-of-place when workspace
// allows: reads stream from the conv intermediate (MALL-resident, pass1 just
// wrote it), spike writes go nontemporal to d_out (never re-read; don't evict
// the read-set from L3). src==dst is the exact R0 in-place fallback (loads of
// batch k+1 issue before stores of batch k -> distinct addresses, safe).
__global__ __launch_bounds__(256)
void spiking_scan_pass2(const float* __restrict__ src, float* __restrict__ dst) {
    const int idx = blockIdx.x * 256 + threadIdx.x;   // 0..65535
    const float4* ps = (const float4*)src + idx;      // column stride CHW/4
    vfloat4* pd = (vfloat4*)dst + idx;
    float sx = 0.f, sy = 0.f, sz = 0.f, sw = 0.f;
    float4 v[8], nv[8];
#pragma unroll
    for (int i = 0; i < 8; ++i) v[i] = ps[(size_t)i * (CHW / 4)];
#pragma unroll 1
    for (int tb = 0; tb < 15; ++tb) {
#pragma unroll
        for (int i = 0; i < 8; ++i) nv[i] = ps[(size_t)((tb + 1) * 8 + i) * (CHW / 4)];
#pragma unroll
        for (int i = 0; i < 8; ++i) {
            vfloat4 o;
            sx += v[i].x; bool a0 = (sx >= 8.0f); o.x = a0 ? 1.f : 0.f; sx = a0 ? 0.f : sx; sx = fmaxf(sx, -1.f);
            sy += v[i].y; bool a1 = (sy >= 8.0f); o.y = a1 ? 1.f : 0.f; sy = a1 ? 0.f : sy; sy = fmaxf(sy, -1.f);
            sz += v[i].z; bool a2 = (sz >= 8.0f); o.z = a2 ? 1.f : 0.f; sz = a2 ? 0.f : sz; sz = fmaxf(sz, -1.f);
            sw += v[i].w; bool a3 = (sw >= 8.0f); o.w = a3 ? 1.f : 0.f; sw = a3 ? 0.f : sw; sw = fmaxf(sw, -1.f);
            __builtin_nontemporal_store(o, &pd[(size_t)(tb * 8 + i) * (CHW / 4)]);
        }
#pragma unroll
        for (int i = 0; i < 8; ++i) v[i] = nv[i];
    }
#pragma unroll
    for (int i = 0; i < 8; ++i) {
        vfloat4 o;
        sx += v[i].x; bool a0 = (sx >= 8.0f); o.x = a0 ? 1.f : 0.f; sx = a0 ? 0.f : sx; sx = fmaxf(sx, -1.f);
        sy += v[i].y; bool a1 = (sy >= 8.0f); o.y = a1 ? 1.f : 0.f; sy = a1 ? 0.f : sy; sy = fmaxf(sy, -1.f);
        sz += v[i].z; bool a2 = (sz >= 8.0f); o.z = a2 ? 1.f : 0.f; sz = a2 ? 0.f : sz; sz = fmaxf(sz, -1.f);
        sw += v[i].w; bool a3 = (sw >= 8.0f); o.w = a3 ? 1.f : 0.f; sw = a3 ? 0.f : sw; sw = fmaxf(sw, -1.f);
        __builtin_nontemporal_store(o, &pd[(size_t)(120 + i) * (CHW / 4)]);
    }
}

extern "C" void kernel_launch(void* const* d_in, const int* in_sizes, int n_in,
                              void* d_out, int out_size, void* d_ws, size_t ws_size,
                              hipStream_t stream) {
    const float* x = (const float*)d_in[0];   // [128,16,64,64]
    const float* W = (const float*)d_in[1];   // [64,16,3,3]
    const float* b = (const float*)d_in[2];   // [64]
    float* out = (float*)d_out;               // [128,64,64,64]
    float* Wtr = (float*)d_ws;                // 16*16*40*4 = 40960 B

    const size_t CONV_BYTES = (size_t)T_STEPS * CHW * sizeof(float);  // 134 MB
    const size_t CONV_OFF   = 1u << 20;                               // 1 MB align
    const bool   big_ws     = ws_size >= CONV_OFF + CONV_BYTES;
    float* conv = big_ws ? (float*)((char*)d_ws + CONV_OFF) : out;

    transpose_w<<<36, 256, 0, stream>>>(W, Wtr);

    dim3 g1(4, 128, 1);   // 4 tiles x 128 t; co-half split across two launches
    spiking_conv_pass1<<<g1, 512, 0, stream>>>(x, Wtr, b, conv, 0);
    spiking_conv_pass1<<<g1, 512, 0, stream>>>(x, Wtr, b, conv, 1);

    spiking_scan_pass2<<<(CHW / 4) / 256, 256, 0, stream>>>(conv, out);
}

// Round 5
// 272.291 us; speedup vs baseline: 1.0592x; 1.0124x over previous
//
#include <hip/hip_runtime.h>

#define T_STEPS 128
#define CIN     16
#define HH      64
#define WW      64
#define COUT    64
#define HWSZ    (HH * WW)          // 4096
#define CHW     (COUT * HWSZ)      // 262144
#define XCHW    (CIN * HWSZ)       // 65536

// pass-1: block = one t, 32x32 tile, ALL 64 co (two sequential 32-co halves
// over one staged LDS tile); wave-halves own 16 co each within a half.
#define TILE    32
#define HALO    34
#define LSTR    36                  // padded LDS row stride (floats)
#define PLANE   (HALO * LSTR)       // 1224 floats per ci
#define NST     (CIN * HALO * HALO) // 18496 staged elements
#define WBLK    40                  // padded weight block per (co-group-of-4, ci)

typedef float vfloat4 __attribute__((ext_vector_type(4)));  // native vec for NT store

// ---- setup: W[64][16][3][3] -> Wtr[(co>>2)*16+ci][40], inner (co&3)*9+k ----
__global__ void transpose_w(const float* __restrict__ W, float* __restrict__ Wtr) {
    int e = blockIdx.x * 256 + threadIdx.x;     // 0..9215
    if (e >= COUT * CIN * 9) return;
    int co = e / (CIN * 9);
    int r  = e - co * (CIN * 9);
    int ci = r / 9;
    int k  = r - ci * 9;
    Wtr[((co >> 2) * CIN + ci) * WBLK + (co & 3) * 9 + k] = W[e];
}

__global__ __launch_bounds__(512, 4)
void spiking_conv_pass1(const float* __restrict__ x, const float* __restrict__ Wtr,
                        const float* __restrict__ b, float* __restrict__ out) {
    __shared__ float xs[CIN * PLANE];   // 78336 B -> 2 blocks/CU, 16 waves/CU

    const int tid = threadIdx.x;        // 0..511
    const int t   = blockIdx.y;
    const int h0  = (blockIdx.x >> 1) * TILE;
    const int w0  = (blockIdx.x & 1) * TILE;

    // ---- stage all 16 ci (+halo) ONCE; two unrolled load-batches ----
    const float* xt = x + t * XCHW;
    {
        float vbuf[19]; int ibuf[19];
#pragma unroll
        for (int k = 0; k < 18; ++k) {
            unsigned e = tid + k * 512;
            unsigned ci = e / (HALO * HALO);
            unsigned rem = e - ci * (HALO * HALO);
            unsigned r  = rem / HALO;
            unsigned c  = rem - r * HALO;
            int gh = h0 - 1 + (int)r;
            int gw = w0 - 1 + (int)c;
            bool inb = (unsigned)gh < HH && (unsigned)gw < WW;
            vbuf[k] = inb ? xt[ci * HWSZ + gh * WW + gw] : 0.f;
            ibuf[k] = ci * PLANE + r * LSTR + c;
        }
#pragma unroll
        for (int k = 0; k < 18; ++k) xs[ibuf[k]] = vbuf[k];
#pragma unroll
        for (int k = 0; k < 19; ++k) {
            unsigned e = tid + (18 + k) * 512;
            unsigned ci = e / (HALO * HALO);
            unsigned rem = e - ci * (HALO * HALO);
            unsigned r  = rem / HALO;
            unsigned c  = rem - r * HALO;
            int gh = h0 - 1 + (int)r;
            int gw = w0 - 1 + (int)c;
            bool inb = e < NST && (unsigned)gh < HH && (unsigned)gw < WW;
            vbuf[k] = inb ? xt[ci * HWSZ + gh * WW + gw] : 0.f;
            ibuf[k] = (e < NST) ? (int)(ci * PLANE + r * LSTR + c) : -1;
        }
#pragma unroll
        for (int k = 0; k < 19; ++k)
            if (ibuf[k] >= 0) xs[ibuf[k]] = vbuf[k];
    }
    __syncthreads();

    // ---- compute: wave-half picks 16-co group; thread = 1x4 patch ----
    const int cog = __builtin_amdgcn_readfirstlane(tid >> 8);  // 0/1
    const int sp  = tid & 255;
    const int pr0 = sp >> 3;           // 0..31
    const int pc0 = (sp & 7) * 4;      // 0..28
    float* outt = out + t * CHW;

    // Two sequential co-halves over the SAME staged tile: staging cost,
    // barriers, and x HBM fetch all halve vs the split-block version.
    // acc[16][4] is reused -> register pressure unchanged. Half-A stores
    // overlap half-B compute.
#pragma unroll 1
    for (int coh = 0; coh < 2; ++coh) {
        float acc[16][4];
#pragma unroll
        for (int j = 0; j < 16; ++j)
#pragma unroll
            for (int p = 0; p < 4; ++p) acc[j][p] = 0.f;

#pragma unroll 1
        for (int ci = 0; ci < CIN; ++ci) {
            // x patch 3x6: ds_read_b128 + ds_read_b64 per row
            float xv[3][6];
#pragma unroll
            for (int dr = 0; dr < 3; ++dr) {
                const float* row = &xs[ci * PLANE + (pr0 + dr) * LSTR + pc0];
                float4 a  = *(const float4*)row;
                float2 c2 = *(const float2*)(row + 4);
                xv[dr][0] = a.x;  xv[dr][1] = a.y;
                xv[dr][2] = a.z;  xv[dr][3] = a.w;
                xv[dr][4] = c2.x; xv[dr][5] = c2.y;
            }
            // 4 co-groups of 4: contiguous 36-float scalar loads (wide s_load)
#pragma unroll
            for (int g = 0; g < 4; ++g) {
                const int g4 = coh * 8 + cog * 4 + g;      // block-uniform
                const float* wb = Wtr + (g4 * CIN + ci) * WBLK;
                float w[36];
#pragma unroll
                for (int i = 0; i < 36; ++i) w[i] = wb[i];
#pragma unroll
                for (int jj = 0; jj < 4; ++jj)
#pragma unroll
                    for (int ky = 0; ky < 3; ++ky)
#pragma unroll
                        for (int kx = 0; kx < 3; ++kx) {
                            const float wv = w[jj * 9 + ky * 3 + kx];
#pragma unroll
                            for (int p = 0; p < 4; ++p)
                                acc[g * 4 + jj][p] += wv * xv[ky][kx + p];
                        }
            }
        }

        // ---- epilogue: +bias, float4 stores ----
#pragma unroll
        for (int g = 0; g < 4; ++g)
#pragma unroll
            for (int jj = 0; jj < 4; ++jj) {
                const int co = coh * 32 + cog * 16 + g * 4 + jj;
                const float bias = b[co];
                float4 o;
                o.x = acc[g * 4 + jj][0] + bias;
                o.y = acc[g * 4 + jj][1] + bias;
                o.z = acc[g * 4 + jj][2] + bias;
                o.w = acc[g * 4 + jj][3] + bias;
                *(float4*)&outt[co * HWSZ + (h0 + pr0) * WW + (w0 + pc0)] = o;
            }
    }
}

// Scan, float4-batch, src/dst split. Out-of-place when workspace allows:
// reads stream from the conv intermediate (MALL-resident, pass1 just wrote
// it), spike writes go nontemporal to d_out. src==dst is the safe in-place
// fallback (loads of batch k+1 issue before stores of batch k).
__global__ __launch_bounds__(256)
void spiking_scan_pass2(const float* __restrict__ src, float* __restrict__ dst) {
    const int idx = blockIdx.x * 256 + threadIdx.x;   // 0..65535
    const float4* ps = (const float4*)src + idx;      // column stride CHW/4
    vfloat4* pd = (vfloat4*)dst + idx;
    float sx = 0.f, sy = 0.f, sz = 0.f, sw = 0.f;
    float4 v[8], nv[8];
#pragma unroll
    for (int i = 0; i < 8; ++i) v[i] = ps[(size_t)i * (CHW / 4)];
#pragma unroll 1
    for (int tb = 0; tb < 15; ++tb) {
#pragma unroll
        for (int i = 0; i < 8; ++i) nv[i] = ps[(size_t)((tb + 1) * 8 + i) * (CHW / 4)];
#pragma unroll
        for (int i = 0; i < 8; ++i) {
            vfloat4 o;
            sx += v[i].x; bool a0 = (sx >= 8.0f); o.x = a0 ? 1.f : 0.f; sx = a0 ? 0.f : sx; sx = fmaxf(sx, -1.f);
            sy += v[i].y; bool a1 = (sy >= 8.0f); o.y = a1 ? 1.f : 0.f; sy = a1 ? 0.f : sy; sy = fmaxf(sy, -1.f);
            sz += v[i].z; bool a2 = (sz >= 8.0f); o.z = a2 ? 1.f : 0.f; sz = a2 ? 0.f : sz; sz = fmaxf(sz, -1.f);
            sw += v[i].w; bool a3 = (sw >= 8.0f); o.w = a3 ? 1.f : 0.f; sw = a3 ? 0.f : sw; sw = fmaxf(sw, -1.f);
            __builtin_nontemporal_store(o, &pd[(size_t)(tb * 8 + i) * (CHW / 4)]);
        }
#pragma unroll
        for (int i = 0; i < 8; ++i) v[i] = nv[i];
    }
#pragma unroll
    for (int i = 0; i < 8; ++i) {
        vfloat4 o;
        sx += v[i].x; bool a0 = (sx >= 8.0f); o.x = a0 ? 1.f : 0.f; sx = a0 ? 0.f : sx; sx = fmaxf(sx, -1.f);
        sy += v[i].y; bool a1 = (sy >= 8.0f); o.y = a1 ? 1.f : 0.f; sy = a1 ? 0.f : sy; sy = fmaxf(sy, -1.f);
        sz += v[i].z; bool a2 = (sz >= 8.0f); o.z = a2 ? 1.f : 0.f; sz = a2 ? 0.f : sz; sz = fmaxf(sz, -1.f);
        sw += v[i].w; bool a3 = (sw >= 8.0f); o.w = a3 ? 1.f : 0.f; sw = a3 ? 0.f : sw; sw = fmaxf(sw, -1.f);
        __builtin_nontemporal_store(o, &pd[(size_t)(120 + i) * (CHW / 4)]);
    }
}

extern "C" void kernel_launch(void* const* d_in, const int* in_sizes, int n_in,
                              void* d_out, int out_size, void* d_ws, size_t ws_size,
                              hipStream_t stream) {
    const float* x = (const float*)d_in[0];   // [128,16,64,64]
    const float* W = (const float*)d_in[1];   // [64,16,3,3]
    const float* b = (const float*)d_in[2];   // [64]
    float* out = (float*)d_out;               // [128,64,64,64]
    float* Wtr = (float*)d_ws;                // 16*16*40*4 = 40960 B

    const size_t CONV_BYTES = (size_t)T_STEPS * CHW * sizeof(float);  // 134 MB
    const size_t CONV_OFF   = 1u << 20;                               // 1 MB align
    const bool   big_ws     = ws_size >= CONV_OFF + CONV_BYTES;
    float* conv = big_ws ? (float*)((char*)d_ws + CONV_OFF) : out;

    transpose_w<<<36, 256, 0, stream>>>(W, Wtr);

    dim3 g1(4, 128);   // 4 tiles x 128 t = 512 blocks (2/CU, one round)
    spiking_conv_pass1<<<g1, 512, 0, stream>>>(x, Wtr, b, conv);

    spiking_scan_pass2<<<(CHW / 4) / 256, 256, 0, stream>>>(conv, out);
}

// Round 6
// 257.640 us; speedup vs baseline: 1.1195x; 1.0569x over previous
//
#include <hip/hip_runtime.h>

#define T_STEPS 128
#define CIN     16
#define HH      64
#define WW      64
#define COUT    64
#define HWSZ    (HH * WW)          // 4096
#define CHW     (COUT * HWSZ)      // 262144
#define XCHW    (CIN * HWSZ)       // 65536

// pass-1: block = one t, 16x32 tile, all 64 co. 8 waves; each wave owns one
// 8-co set (wave w-footprint per ci = 72 floats -> fits SGPRs WITH prefetch
// headroom, unlike the old 144-float/wave layout that pinned SGPR=112 and
// forced a cold s_load stall at every g-block). Thread = 1x8 spatial patch.
#define TILEH   16
#define TILEW   32
#define HALOH   18
#define HALOW   34
#define LSTR    36                    // padded LDS row stride (floats)
#define PLANE   (HALOH * LSTR)        // 648 floats per ci
#define NST     (CIN * HALOH * HALOW) // 9792 staged elements
#define WBLK    40                    // padded weight block per (co-group-of-4, ci)

typedef float vfloat4 __attribute__((ext_vector_type(4)));  // native vec for NT store

// ---- setup: W[64][16][3][3] -> Wtr[(co>>2)*16+ci][40], inner (co&3)*9+k ----
__global__ void transpose_w(const float* __restrict__ W, float* __restrict__ Wtr) {
    int e = blockIdx.x * 256 + threadIdx.x;     // 0..9215
    if (e >= COUT * CIN * 9) return;
    int co = e / (CIN * 9);
    int r  = e - co * (CIN * 9);
    int ci = r / 9;
    int k  = r - ci * 9;
    Wtr[((co >> 2) * CIN + ci) * WBLK + (co & 3) * 9 + k] = W[e];
}

__global__ __launch_bounds__(512, 4)
void spiking_conv_pass1(const float* __restrict__ x, const float* __restrict__ Wtr,
                        const float* __restrict__ b, float* __restrict__ out) {
    __shared__ float xs[CIN * PLANE];   // 41472 B -> 2 blocks/CU (reg-capped anyway)

    const int tid = threadIdx.x;        // 0..511
    const int t   = blockIdx.y;
    const int h0  = (blockIdx.x >> 1) * TILEH;   // 4 row-bands
    const int w0  = (blockIdx.x & 1) * TILEW;    // 2 col-halves

    // ---- stage all 16 ci (+halo) once: 9792 elements, 2 batches of 10 ----
    const float* xt = x + t * XCHW;
    {
        float vbuf[10]; int ibuf[10];
#pragma unroll
        for (int k = 0; k < 10; ++k) {
            unsigned e = tid + k * 512;
            unsigned ci = e / (HALOH * HALOW);
            unsigned rem = e - ci * (HALOH * HALOW);
            unsigned r  = rem / HALOW;
            unsigned c  = rem - r * HALOW;
            int gh = h0 - 1 + (int)r;
            int gw = w0 - 1 + (int)c;
            bool inb = (unsigned)gh < HH && (unsigned)gw < WW;
            vbuf[k] = inb ? xt[ci * HWSZ + gh * WW + gw] : 0.f;
            ibuf[k] = ci * PLANE + r * LSTR + c;
        }
#pragma unroll
        for (int k = 0; k < 10; ++k) xs[ibuf[k]] = vbuf[k];
#pragma unroll
        for (int k = 0; k < 10; ++k) {
            unsigned e = tid + (10 + k) * 512;
            unsigned ci = e / (HALOH * HALOW);
            unsigned rem = e - ci * (HALOH * HALOW);
            unsigned r  = rem / HALOW;
            unsigned c  = rem - r * HALOW;
            int gh = h0 - 1 + (int)r;
            int gw = w0 - 1 + (int)c;
            bool inb = e < NST && (unsigned)gh < HH && (unsigned)gw < WW;
            vbuf[k] = inb ? xt[ci * HWSZ + gh * WW + gw] : 0.f;
            ibuf[k] = (e < NST) ? (int)(ci * PLANE + r * LSTR + c) : -1;
        }
#pragma unroll
        for (int k = 0; k < 10; ++k)
            if (ibuf[k] >= 0) xs[ibuf[k]] = vbuf[k];
    }
    __syncthreads();

    // ---- compute: wave = one 8-co set; thread = 1x8 patch ----
    const int cog = __builtin_amdgcn_readfirstlane(tid >> 6);  // 0..7 (one per wave)
    const int ln  = tid & 63;
    const int pr0 = ln >> 2;            // 0..15
    const int pc0 = (ln & 3) * 8;       // 0,8,16,24
    float* outt = out + t * CHW;

    float acc[8][8];
#pragma unroll
    for (int j = 0; j < 8; ++j)
#pragma unroll
        for (int p = 0; p < 8; ++p) acc[j][p] = 0.f;

#pragma unroll 1
    for (int ci = 0; ci < CIN; ++ci) {
        // x patch 3x10: 2x ds_read_b128 + ds_read_b64 per row (32B-aligned)
        float xv[3][10];
#pragma unroll
        for (int dr = 0; dr < 3; ++dr) {
            const float* row = &xs[ci * PLANE + (pr0 + dr) * LSTR + pc0];
            float4 a  = *(const float4*)row;
            float4 b4 = *(const float4*)(row + 4);
            float2 c2 = *(const float2*)(row + 8);
            xv[dr][0] = a.x;  xv[dr][1] = a.y;  xv[dr][2] = a.z;  xv[dr][3] = a.w;
            xv[dr][4] = b4.x; xv[dr][5] = b4.y; xv[dr][6] = b4.z; xv[dr][7] = b4.w;
            xv[dr][8] = c2.x; xv[dr][9] = c2.y;
        }
        // 2 co-groups of 4 per wave: 72 w floats total -> SGPR-resident with
        // prefetch headroom; 288 FMAs per 36-float block hide the s_load.
#pragma unroll
        for (int g = 0; g < 2; ++g) {
            const int g4 = cog * 2 + g;                    // wave-uniform
            const float* wb = Wtr + (g4 * CIN + ci) * WBLK;
            float w[36];
#pragma unroll
            for (int i = 0; i < 36; ++i) w[i] = wb[i];
#pragma unroll
            for (int jj = 0; jj < 4; ++jj)
#pragma unroll
                for (int ky = 0; ky < 3; ++ky)
#pragma unroll
                    for (int kx = 0; kx < 3; ++kx) {
                        const float wv = w[jj * 9 + ky * 3 + kx];
#pragma unroll
                        for (int p = 0; p < 8; ++p)
                            acc[g * 4 + jj][p] += wv * xv[ky][kx + p];
                    }
        }
    }

    // ---- epilogue: +bias, 2x float4 stores per co ----
#pragma unroll
    for (int g = 0; g < 2; ++g)
#pragma unroll
        for (int jj = 0; jj < 4; ++jj) {
            const int co = cog * 8 + g * 4 + jj;
            const float bias = b[co];
            float* op = &outt[co * HWSZ + (h0 + pr0) * WW + (w0 + pc0)];
            float4 o0, o1;
            o0.x = acc[g * 4 + jj][0] + bias;
            o0.y = acc[g * 4 + jj][1] + bias;
            o0.z = acc[g * 4 + jj][2] + bias;
            o0.w = acc[g * 4 + jj][3] + bias;
            o1.x = acc[g * 4 + jj][4] + bias;
            o1.y = acc[g * 4 + jj][5] + bias;
            o1.z = acc[g * 4 + jj][6] + bias;
            o1.w = acc[g * 4 + jj][7] + bias;
            *(float4*)op = o0;
            *(float4*)(op + 4) = o1;
        }
}

// Scan, float4-batch, src/dst split. Out-of-place when workspace allows:
// reads stream from the conv intermediate (MALL-resident, pass1 just wrote
// it), spike writes go nontemporal to d_out. src==dst is the safe in-place
// fallback (loads of batch k+1 issue before stores of batch k).
__global__ __launch_bounds__(256)
void spiking_scan_pass2(const float* __restrict__ src, float* __restrict__ dst) {
    const int idx = blockIdx.x * 256 + threadIdx.x;   // 0..65535
    const float4* ps = (const float4*)src + idx;      // column stride CHW/4
    vfloat4* pd = (vfloat4*)dst + idx;
    float sx = 0.f, sy = 0.f, sz = 0.f, sw = 0.f;
    float4 v[8], nv[8];
#pragma unroll
    for (int i = 0; i < 8; ++i) v[i] = ps[(size_t)i * (CHW / 4)];
#pragma unroll 1
    for (int tb = 0; tb < 15; ++tb) {
#pragma unroll
        for (int i = 0; i < 8; ++i) nv[i] = ps[(size_t)((tb + 1) * 8 + i) * (CHW / 4)];
#pragma unroll
        for (int i = 0; i < 8; ++i) {
            vfloat4 o;
            sx += v[i].x; bool a0 = (sx >= 8.0f); o.x = a0 ? 1.f : 0.f; sx = a0 ? 0.f : sx; sx = fmaxf(sx, -1.f);
            sy += v[i].y; bool a1 = (sy >= 8.0f); o.y = a1 ? 1.f : 0.f; sy = a1 ? 0.f : sy; sy = fmaxf(sy, -1.f);
            sz += v[i].z; bool a2 = (sz >= 8.0f); o.z = a2 ? 1.f : 0.f; sz = a2 ? 0.f : sz; sz = fmaxf(sz, -1.f);
            sw += v[i].w; bool a3 = (sw >= 8.0f); o.w = a3 ? 1.f : 0.f; sw = a3 ? 0.f : sw; sw = fmaxf(sw, -1.f);
            __builtin_nontemporal_store(o, &pd[(size_t)(tb * 8 + i) * (CHW / 4)]);
        }
#pragma unroll
        for (int i = 0; i < 8; ++i) v[i] = nv[i];
    }
#pragma unroll
    for (int i = 0; i < 8; ++i) {
        vfloat4 o;
        sx += v[i].x; bool a0 = (sx >= 8.0f); o.x = a0 ? 1.f : 0.f; sx = a0 ? 0.f : sx; sx = fmaxf(sx, -1.f);
        sy += v[i].y; bool a1 = (sy >= 8.0f); o.y = a1 ? 1.f : 0.f; sy = a1 ? 0.f : sy; sy = fmaxf(sy, -1.f);
        sz += v[i].z; bool a2 = (sz >= 8.0f); o.z = a2 ? 1.f : 0.f; sz = a2 ? 0.f : sz; sz = fmaxf(sz, -1.f);
        sw += v[i].w; bool a3 = (sw >= 8.0f); o.w = a3 ? 1.f : 0.f; sw = a3 ? 0.f : sw; sw = fmaxf(sw, -1.f);
        __builtin_nontemporal_store(o, &pd[(size_t)(120 + i) * (CHW / 4)]);
    }
}

extern "C" void kernel_launch(void* const* d_in, const int* in_sizes, int n_in,
                              void* d_out, int out_size, void* d_ws, size_t ws_size,
                              hipStream_t stream) {
    const float* x = (const float*)d_in[0];   // [128,16,64,64]
    const float* W = (const float*)d_in[1];   // [64,16,3,3]
    const float* b = (const float*)d_in[2];   // [64]
    float* out = (float*)d_out;               // [128,64,64,64]
    float* Wtr = (float*)d_ws;                // 16*16*40*4 = 40960 B

    const size_t CONV_BYTES = (size_t)T_STEPS * CHW * sizeof(float);  // 134 MB
    const size_t CONV_OFF   = 1u << 20;                               // 1 MB align
    const bool   big_ws     = ws_size >= CONV_OFF + CONV_BYTES;
    float* conv = big_ws ? (float*)((char*)d_ws + CONV_OFF) : out;

    transpose_w<<<36, 256, 0, stream>>>(W, Wtr);

    dim3 g1(8, 128);   // 8 tiles (4 row-bands x 2 col-halves) x 128 t = 1024 blocks
    spiking_conv_pass1<<<g1, 512, 0, stream>>>(x, Wtr, b, conv);

    spiking_scan_pass2<<<(CHW / 4) / 256, 256, 0, stream>>>(conv, out);
}